// Round 16
// baseline (230.124 us; speedup 1.0000x reference)
//
#include <hip/hip_runtime.h>
#include <math.h>

#define EMB 256

typedef _Float16 half8 __attribute__((ext_vector_type(8)));
typedef float f32x4 __attribute__((ext_vector_type(4)));

// 8 f32 -> hi/lo fp16 split: x ~= hi + lo to ~2^-22 rel.
__device__ __forceinline__ void split8(const f32x4 a, const f32x4 b,
                                       half8& hi, half8& lo) {
#pragma unroll
    for (int i = 0; i < 4; ++i) {
        hi[i]     = (_Float16)a[i];
        lo[i]     = (_Float16)(a[i] - (float)hi[i]);
        hi[4 + i] = (_Float16)b[i];
        lo[4 + i] = (_Float16)(b[i] - (float)hi[4 + i]);
    }
}

// Pre-split W (Wh,Wt: 256x256 f32) into granule-swizzled f16 hi/lo:
// dst[r*512 + c*64 + g'*8 ..+8), g = part*4+seg, g' = g ^ (r&7).
__global__ void presplit_w(const float* __restrict__ Wh, const float* __restrict__ Wt,
                           _Float16* __restrict__ Whs, _Float16* __restrict__ Wts)
{
    const int g = blockIdx.x * 256 + threadIdx.x;
    const int m = g >> 5;                  // 0..511
    const int cs = g & 31;
    const int c = cs >> 2, seg = cs & 3;
    const float* src = (m < 256) ? Wh : Wt;
    _Float16* dst    = (m < 256) ? Whs : Wts;
    const int r = m & 255;

    const float* s = src + (size_t)r * EMB + c * 32 + seg * 8;
    const f32x4 v0 = *(const f32x4*)s;
    const f32x4 v1 = *(const f32x4*)(s + 4);
    half8 hi, lo;
    split8(v0, v1, hi, lo);
    _Float16* d = dst + (size_t)r * 512 + c * 64;
    const int sw = r & 7;
    *(half8*)(d + ((seg       ^ sw) << 3)) = hi;
    *(half8*)(d + (((4 + seg) ^ sw) << 3)) = lo;
}

// Register-resident-B GEMM, 32 KB LDS (well inside the proven envelope).
// Block = variant v (mat = v>>2; 64-col n-block = v&3) x slot (bid&63);
// persistent over m-tiles mt = slot, slot+64, ... Each wave owns 32 cols:
// B = 32 half8 VGPRs (2 n-frags x 8 chunks x hi/lo), loaded ONCE from the
// presplit Ws with the same granule-XOR formula the proven LDS path used.
// K-loop = R7's proven A path only: global->reg->split->ds_write f16 into a
// 2x16KB double buffer, ONE __syncthreads per chunk (its implicit waits also
// drain the previous chunk's ds_reads), A-reg prefetch covered by 24 MFMA.
// bid%8 == slot%8 -> all 8 variants of a slot share one XCD's L2 -> X is
// HBM-fetched once. 3-term split-f16 MFMA (hi*hi + hi*lo + lo*hi).
__global__ __launch_bounds__(256, 2)
void gemm_breg(const float* __restrict__ X,
               const _Float16* __restrict__ Whs, const _Float16* __restrict__ Wts,
               const float* __restrict__ bh, const float* __restrict__ bt,
               float* __restrict__ Hout, float* __restrict__ Tout,
               int M, int mtiles)
{
    __shared__ __align__(16) _Float16 Axd[2][128 * 64];   // 2 x 16 KB

    const int bid = blockIdx.x;
    const int slot = bid & 63;
    const int v = bid >> 6;            // 0..7
    const int mat = v >> 2;            // 0 = head, 1 = tail
    const int n0g = (v & 3) << 6;      // 0,64,128,192

    const _Float16* __restrict__ Ws = mat ? Wts : Whs;
    const float* __restrict__ bias  = mat ? bt : bh;
    float* __restrict__ OUT         = mat ? Tout : Hout;

    const int tid = threadIdx.x;
    const int lane = tid & 63;
    const int wv = tid >> 6;
    const int wm = (wv >> 1) << 6;     // 0 / 64
    const int wn = (wv & 1) << 5;      // 0 / 32
    const int l15 = lane & 15, l4 = lane >> 4;

    // ---- B resident in registers: 32 x half8, loaded once ----
    half8 Bh_[2][8], Bl_[2][8];
#pragma unroll
    for (int j = 0; j < 2; ++j) {
        const int row = n0g + wn + j * 16 + l15;
        const char* rb = (const char*)Ws + (size_t)row * 1024;
        const int r7 = row & 7;
#pragma unroll
        for (int c = 0; c < 8; ++c) {
            Bh_[j][c] = *(const half8*)(rb + c * 128 + (((l4    ) ^ r7) << 4));
            Bl_[j][c] = *(const half8*)(rb + c * 128 + (((l4 + 4) ^ r7) << 4));
        }
    }

    float bv[2];
#pragma unroll
    for (int j = 0; j < 2; ++j) bv[j] = bias[n0g + wn + j * 16 + l15];

    // A staging map (R7-proven): thread -> row ar = tid>>1, k-half tid&1
    const int ar = tid >> 1;
    const int ahalf = tid & 1;
    const int ar7 = ar & 7;
    const int s0 = ahalf * 2, s1 = s0 + 1;
    const int oh0 = ((s0       ^ ar7) << 4), ol0 = (((4 + s0) ^ ar7) << 4);
    const int oh1 = ((s1       ^ ar7) << 4), ol1 = (((4 + s1) ^ ar7) << 4);

    for (int mt = slot; mt < mtiles; mt += 64) {
        const int m0 = mt << 7;
        const int gmA = m0 + ar;
        const float* aSrc = X + (size_t)(gmA < M ? gmA : M - 1) * EMB + ahalf * 16;

        f32x4 acc[4][2];
#pragma unroll
        for (int i = 0; i < 4; ++i)
#pragma unroll
            for (int j = 0; j < 2; ++j) acc[i][j] = (f32x4){0.f, 0.f, 0.f, 0.f};

        // tile prologue: chunk-0 A regs (exposed once per tile, ~12 tiles)
        f32x4 xg[4];
#pragma unroll
        for (int p = 0; p < 4; ++p) xg[p] = *(const f32x4*)(aSrc + p * 4);

#pragma unroll
        for (int c = 0; c < 8; ++c) {
            // split + ds_write chunk c into buf (c&1). Safe: last reads of
            // this buf (chunk c-2) were drained by chunk c-1's barrier.
            {
                char* aDst = (char*)&Axd[c & 1][0] + ar * 128;
                half8 hi0, lo0, hi1, lo1;
                split8(xg[0], xg[1], hi0, lo0);
                split8(xg[2], xg[3], hi1, lo1);
                *(half8*)(aDst + oh0) = hi0;
                *(half8*)(aDst + ol0) = lo0;
                *(half8*)(aDst + oh1) = hi1;
                *(half8*)(aDst + ol1) = lo1;
            }
            __syncthreads();   // writes visible; prev reads drained

            // prefetch next chunk's A regs (drains at next split8)
            if (c < 7) {
                const float* an = aSrc + (c + 1) * 32;
#pragma unroll
                for (int p = 0; p < 4; ++p) xg[p] = *(const f32x4*)(an + p * 4);
            }

            const char* Ab = (const char*)&Axd[c & 1][0];
            half8 ahh[4], ahl[4];
#pragma unroll
            for (int fi = 0; fi < 4; ++fi) {
                const int row = wm + fi * 16 + l15;
                const char* rb2 = Ab + row * 128;
                ahh[fi] = *(const half8*)(rb2 + (((l4    ) ^ (row & 7)) << 4));
                ahl[fi] = *(const half8*)(rb2 + (((l4 + 4) ^ (row & 7)) << 4));
            }
#pragma unroll
            for (int j = 0; j < 2; ++j)
#pragma unroll
                for (int i = 0; i < 4; ++i) {
                    acc[i][j] = __builtin_amdgcn_mfma_f32_16x16x32_f16(ahh[i], Bh_[j][c], acc[i][j], 0, 0, 0);
                    acc[i][j] = __builtin_amdgcn_mfma_f32_16x16x32_f16(ahh[i], Bl_[j][c], acc[i][j], 0, 0, 0);
                    acc[i][j] = __builtin_amdgcn_mfma_f32_16x16x32_f16(ahl[i], Bh_[j][c], acc[i][j], 0, 0, 0);
                }
        }

        // epilogue: C/D layout col = lane&15, row = (lane>>4)*4 + reg (m89).
        // Stores fire-and-forget; next tile's barrier machinery absorbs them.
#pragma unroll
        for (int i = 0; i < 4; ++i) {
            const int rbase = m0 + wm + i * 16 + l4 * 4;
#pragma unroll
            for (int rg = 0; rg < 4; ++rg) {
                const int gr = rbase + rg;
                if (gr < M) {
                    float* dst = &OUT[(size_t)gr * EMB + n0g + wn];
#pragma unroll
                    for (int j = 0; j < 2; ++j)
                        dst[j * 16 + l15] = acc[i][j][rg] + bv[j];
                }
            }
        }
    }
}

// Four edges per wave: 12 outstanding row-gathers for memory-level parallelism.
__global__ __launch_bounds__(256)
void edge_score4(const float* __restrict__ H, const float* __restrict__ T,
                 const float* __restrict__ rel, const int* __restrict__ ei,
                 const int* __restrict__ et, float* __restrict__ out, int E)
{
    const int lane = threadIdx.x & 63;
    const int wid = threadIdx.x >> 6;
    const int base = (blockIdx.x * 4 + wid) * 4;
    if (base >= E) return;

    int e[4];
#pragma unroll
    for (int u = 0; u < 4; ++u) {
        int eu = base + u;
        e[u] = eu < E ? eu : E - 1;      // clamp: dup work, identical writes
    }

    const int lo = lane * 4;
    float4 h[4], t[4], g[4];
#pragma unroll
    for (int u = 0; u < 4; ++u) h[u] = *(const float4*)&H[(size_t)ei[e[u]] * EMB + lo];
#pragma unroll
    for (int u = 0; u < 4; ++u) t[u] = *(const float4*)&T[(size_t)ei[E + e[u]] * EMB + lo];
#pragma unroll
    for (int u = 0; u < 4; ++u) g[u] = *(const float4*)&rel[(size_t)et[e[u]] * EMB + lo];

    float p[4];
#pragma unroll
    for (int u = 0; u < 4; ++u)
        p[u] = h[u].x * g[u].x * t[u].x + h[u].y * g[u].y * t[u].y
             + h[u].z * g[u].z * t[u].z + h[u].w * g[u].w * t[u].w;

#pragma unroll
    for (int off = 32; off > 0; off >>= 1) {
#pragma unroll
        for (int u = 0; u < 4; ++u) p[u] += __shfl_xor(p[u], off, 64);
    }
    if (lane == 0) {
#pragma unroll
        for (int u = 0; u < 4; ++u)
            out[e[u]] = 1.0f / (1.0f + expf(-p[u]));
    }
}

// Last-resort fallback: one block per edge, direct fp32 matvecs.
__global__ __launch_bounds__(256)
void edge_direct(const float* __restrict__ X, const int* __restrict__ ei,
                 const int* __restrict__ et,
                 const float* __restrict__ Wh, const float* __restrict__ bh,
                 const float* __restrict__ Wt, const float* __restrict__ bt,
                 const float* __restrict__ rel, float* __restrict__ out, int E)
{
    __shared__ float xsrc[EMB], xdst[EMB];
    __shared__ float red[256];
    const int e = blockIdx.x;
    const int tid = threadIdx.x;
    const int src = ei[e], dst = ei[E + e], r = et[e];

    xsrc[tid] = X[(size_t)src * EMB + tid];
    xdst[tid] = X[(size_t)dst * EMB + tid];
    __syncthreads();

    float ah = 0.f, at = 0.f;
    const float* wh = Wh + (size_t)tid * EMB;
    const float* wt = Wt + (size_t)tid * EMB;
#pragma unroll 8
    for (int k = 0; k < EMB; k += 4) {
        float4 w4 = *(const float4*)&wh[k];
        ah += w4.x * xsrc[k] + w4.y * xsrc[k + 1] + w4.z * xsrc[k + 2] + w4.w * xsrc[k + 3];
        float4 v4 = *(const float4*)&wt[k];
        at += v4.x * xdst[k] + v4.y * xdst[k + 1] + v4.z * xdst[k + 2] + v4.w * xdst[k + 3];
    }
    red[tid] = (ah + bh[tid]) * rel[(size_t)r * EMB + tid] * (at + bt[tid]);
    __syncthreads();
    for (int s2 = 128; s2 > 0; s2 >>= 1) {
        if (tid < s2) red[tid] += red[tid + s2];
        __syncthreads();
    }
    if (tid == 0) out[e] = 1.0f / (1.0f + expf(-red[0]));
}

extern "C" void kernel_launch(void* const* d_in, const int* in_sizes, int n_in,
                              void* d_out, int out_size, void* d_ws, size_t ws_size,
                              hipStream_t stream) {
    const float* x   = (const float*)d_in[0];
    const int*   ei  = (const int*)d_in[1];
    const int*   et  = (const int*)d_in[2];
    const float* Wh  = (const float*)d_in[3];
    const float* bh  = (const float*)d_in[4];
    const float* Wt  = (const float*)d_in[5];
    const float* bt  = (const float*)d_in[6];
    const float* rel = (const float*)d_in[7];
    float* out = (float*)d_out;

    const int M = in_sizes[0] / EMB;   // 100000 nodes
    const int E = in_sizes[2];         // 250000 edges

    const size_t szHT = (size_t)2 * M * EMB * sizeof(float);        // H + T
    const size_t szWs = (size_t)2 * 256 * 512 * sizeof(_Float16);   // Whs+Wts

    if (ws_size >= szHT + szWs) {
        float* H = (float*)d_ws;
        float* T = H + (size_t)M * EMB;
        _Float16* Whs = (_Float16*)((char*)d_ws + szHT);
        _Float16* Wts = Whs + (size_t)256 * 512;

        presplit_w<<<64, 256, 0, stream>>>(Wh, Wt, Whs, Wts);
        const int mtiles = (M + 127) / 128;
        gemm_breg<<<512, 256, 0, stream>>>(x, Whs, Wts, bh, bt, H, T, M, mtiles);
        edge_score4<<<(E + 15) / 16, 256, 0, stream>>>(H, T, rel, ei, et, out, E);
    } else {
        edge_direct<<<E, 256, 0, stream>>>(x, ei, et, Wh, bh, Wt, bt, rel, out, E);
    }
}

// Round 18
// 176.822 us; speedup vs baseline: 1.3014x; 1.3014x over previous
//
#include <hip/hip_runtime.h>
#include <math.h>

#define EMB 256

typedef _Float16 half8 __attribute__((ext_vector_type(8)));
typedef float f32x4 __attribute__((ext_vector_type(4)));

// ---------- async global->LDS, 16B per lane ----------
__device__ __forceinline__ void gload_lds16(const void* gsrc, void* lds) {
    __builtin_amdgcn_global_load_lds(
        (const __attribute__((address_space(1))) void*)gsrc,
        (__attribute__((address_space(3))) void*)lds,
        16, 0, 0);
}

// 8 f32 -> hi/lo fp16 split: x ~= hi + lo to ~2^-22 rel.
__device__ __forceinline__ void split8(const f32x4 a, const f32x4 b,
                                       half8& hi, half8& lo) {
#pragma unroll
    for (int i = 0; i < 4; ++i) {
        hi[i]     = (_Float16)a[i];
        lo[i]     = (_Float16)(a[i] - (float)hi[i]);
        hi[4 + i] = (_Float16)b[i];
        lo[4 + i] = (_Float16)(b[i] - (float)hi[4 + i]);
    }
}

// Pre-split W (Wh,Wt: 256x256 f32) into granule-swizzled f16 hi/lo:
// dst[r*512 + c*64 + g'*8 ..+8), g = part*4+seg, g' = g ^ (r&7).
__global__ void presplit_w(const float* __restrict__ Wh, const float* __restrict__ Wt,
                           _Float16* __restrict__ Whs, _Float16* __restrict__ Wts)
{
    const int g = blockIdx.x * 256 + threadIdx.x;
    const int m = g >> 5;                  // 0..511
    const int cs = g & 31;
    const int c = cs >> 2, seg = cs & 3;
    const float* src = (m < 256) ? Wh : Wt;
    _Float16* dst    = (m < 256) ? Whs : Wts;
    const int r = m & 255;

    const float* s = src + (size_t)r * EMB + c * 32 + seg * 8;
    const f32x4 v0 = *(const f32x4*)s;
    const f32x4 v1 = *(const f32x4*)(s + 4);
    half8 hi, lo;
    split8(v0, v1, hi, lo);
    _Float16* d = dst + (size_t)r * 512 + c * 64;
    const int sw = r & 7;
    *(half8*)(d + ((seg       ^ sw) << 3)) = hi;
    *(half8*)(d + (((4 + seg) ^ sw) << 3)) = lo;
}

// Dual-output GEMM — the verified plateau-minimum configuration (R7: 108 us,
// MfmaUtil ~30%). One block -> 128x128 tile of BOTH H = X*Wh^T + bh and
// T = X*Wt^T + bt. 3-term split-f16 MFMA (hi*hi + hi*lo + lo*hi).
// A: global->reg->split->ds_write f16 (split once per block).
// B: pre-split f16 staged by global_load_lds (zero in-loop VALU).
// Granule-XOR swizzle on all LDS layouts -> conflict-free ds_read_b128.
// Envelope constraints verified across R6-R17: 256 threads,
// __launch_bounds__(256,2), <=80 KB static LDS. (256,4) regressed (R10:
// VGPR forced to 140, occupancy 9.8%); 512-thr (512,2) and >=128 KB LDS
// variants fail to launch in this harness (R13-15, R17).
__global__ __launch_bounds__(256, 2)
void gemm_dual(const float* __restrict__ X,
               const _Float16* __restrict__ Whs, const _Float16* __restrict__ Wts,
               const float* __restrict__ bh, const float* __restrict__ bt,
               float* __restrict__ Hout, float* __restrict__ Tout,
               int M, int nwg)
{
    __shared__ __align__(16) _Float16 Ax[128 * 64];   // 16 KB (hi g0-3, lo g4-7)
    __shared__ __align__(16) _Float16 Bh[128 * 64];   // 16 KB
    __shared__ __align__(16) _Float16 Bt[128 * 64];   // 16 KB

    // bijective XCD swizzle (m204)
    const int fl = blockIdx.x;
    const int q = nwg >> 3, r = nwg & 7;
    const int xcd = fl & 7, ix = fl >> 3;
    const int wg = (xcd < r) ? xcd * (q + 1) + ix
                             : r * (q + 1) + (xcd - r) * q + ix;
    const int n0 = (wg & 1) << 7;
    const int m0 = (wg >> 1) << 7;

    const int tid = threadIdx.x;
    const int lane = tid & 63;
    const int wv = tid >> 6;
    const int wm = (wv >> 1) << 6;
    const int wn = (wv & 1) << 6;
    const int l15 = lane & 15, l4 = lane >> 4;

    // ---- A staging mapping: thread -> (row = tid>>1, 16-float half = tid&1)
    const int ar = tid >> 1;
    const int ahalf = tid & 1;
    const int gmA = m0 + ar;
    const float* aSrc = X + (size_t)(gmA < M ? gmA : M - 1) * EMB + ahalf * 16;
    char* aDst = (char*)Ax + ar * 128;
    const int ar7 = ar & 7;
    const int s0 = ahalf * 2, s1 = s0 + 1;
    const int oh0 = ((s0       ^ ar7) << 4), ol0 = (((4 + s0) ^ ar7) << 4);
    const int oh1 = ((s1       ^ ar7) << 4), ol1 = (((4 + s1) ^ ar7) << 4);

    // ---- B staging mapping: issue i: row = (tid>>3)+32i, phys granule tid&7
    const int brow = tid >> 3, bg = tid & 7;
    const char* bhSrc = (const char*)Whs + (size_t)(n0 + brow) * 1024 + bg * 16;
    const char* btSrc = (const char*)Wts + (size_t)(n0 + brow) * 1024 + bg * 16;
    char* bhDst = (char*)Bh + brow * 128 + bg * 16;
    char* btDst = (char*)Bt + brow * 128 + bg * 16;

    f32x4 accH[4][4], accT[4][4];
#pragma unroll
    for (int i = 0; i < 4; ++i)
#pragma unroll
        for (int j = 0; j < 4; ++j) {
            accH[i][j] = (f32x4){0.f, 0.f, 0.f, 0.f};
            accT[i][j] = (f32x4){0.f, 0.f, 0.f, 0.f};
        }

    // preload A chunk 0 into regs
    f32x4 xg[4];
#pragma unroll
    for (int p = 0; p < 4; ++p) xg[p] = *(const f32x4*)(aSrc + p * 4);

    for (int c = 0; c < 8; ++c) {
        if (c) __syncthreads();          // prev chunk's frag reads done
        // B gloads first: latency hides under the A-split VALU below
        const int cb = c << 7;
#pragma unroll
        for (int i = 0; i < 4; ++i) {
            gload_lds16(bhSrc + (size_t)i * 32768 + cb, bhDst + i * 4096);
            gload_lds16(btSrc + (size_t)i * 32768 + cb, btDst + i * 4096);
        }
        // A split + LDS write (once per block, not per wave)
        {
            half8 hi0, lo0, hi1, lo1;
            split8(xg[0], xg[1], hi0, lo0);
            split8(xg[2], xg[3], hi1, lo1);
            *(half8*)(aDst + oh0) = hi0;
            *(half8*)(aDst + ol0) = lo0;
            *(half8*)(aDst + oh1) = hi1;
            *(half8*)(aDst + ol1) = lo1;
        }
        __syncthreads();                 // drains vmcnt+lgkm: tiles visible

        // prefetch next A chunk (latency hidden under MFMA block)
        if (c < 7) {
            const float* an = aSrc + (c + 1) * 32;
#pragma unroll
            for (int p = 0; p < 4; ++p) xg[p] = *(const f32x4*)(an + p * 4);
        }

        half8 ahh[4], ahl[4];
#pragma unroll
        for (int fi = 0; fi < 4; ++fi) {
            const int row = wm + fi * 16 + l15;
            const char* rb = (const char*)Ax + row * 128;
            ahh[fi] = *(const half8*)(rb + (((l4    ) ^ (row & 7)) << 4));
            ahl[fi] = *(const half8*)(rb + (((l4 + 4) ^ (row & 7)) << 4));
        }
#pragma unroll
        for (int j = 0; j < 4; ++j) {
            const int n = wn + j * 16 + l15;
            const int n7 = n & 7;
            const char* hr = (const char*)Bh + n * 128;
            const char* tr = (const char*)Bt + n * 128;
            const half8 bhh = *(const half8*)(hr + (((l4    ) ^ n7) << 4));
            const half8 bhl = *(const half8*)(hr + (((l4 + 4) ^ n7) << 4));
            const half8 bth = *(const half8*)(tr + (((l4    ) ^ n7) << 4));
            const half8 btl = *(const half8*)(tr + (((l4 + 4) ^ n7) << 4));
#pragma unroll
            for (int i = 0; i < 4; ++i) {
                accH[i][j] = __builtin_amdgcn_mfma_f32_16x16x32_f16(ahh[i], bhh, accH[i][j], 0, 0, 0);
                accH[i][j] = __builtin_amdgcn_mfma_f32_16x16x32_f16(ahh[i], bhl, accH[i][j], 0, 0, 0);
                accH[i][j] = __builtin_amdgcn_mfma_f32_16x16x32_f16(ahl[i], bhh, accH[i][j], 0, 0, 0);
                accT[i][j] = __builtin_amdgcn_mfma_f32_16x16x32_f16(ahh[i], bth, accT[i][j], 0, 0, 0);
                accT[i][j] = __builtin_amdgcn_mfma_f32_16x16x32_f16(ahh[i], btl, accT[i][j], 0, 0, 0);
                accT[i][j] = __builtin_amdgcn_mfma_f32_16x16x32_f16(ahl[i], bth, accT[i][j], 0, 0, 0);
            }
        }
    }

    // epilogue: C/D layout col = lane&15, row = (lane>>4)*4 + reg (m89)
    float bhv[4], btv[4];
#pragma unroll
    for (int j = 0; j < 4; ++j) {
        bhv[j] = bh[n0 + wn + j * 16 + l15];
        btv[j] = bt[n0 + wn + j * 16 + l15];
    }
#pragma unroll
    for (int i = 0; i < 4; ++i) {
        const int rbase = m0 + wm + i * 16 + l4 * 4;
#pragma unroll
        for (int rg = 0; rg < 4; ++rg) {
            const int gr = rbase + rg;
            if (gr < M) {
                float* dh = &Hout[(size_t)gr * EMB + n0 + wn];
                float* dt = &Tout[(size_t)gr * EMB + n0 + wn];
#pragma unroll
                for (int j = 0; j < 4; ++j) {
                    const int col = j * 16 + l15;
                    dh[col] = accH[i][j][rg] + bhv[j];
                    dt[col] = accT[i][j][rg] + btv[j];
                }
            }
        }
    }
}

// Four edges per wave: 12 outstanding row-gathers for memory-level parallelism.
__global__ __launch_bounds__(256)
void edge_score4(const float* __restrict__ H, const float* __restrict__ T,
                 const float* __restrict__ rel, const int* __restrict__ ei,
                 const int* __restrict__ et, float* __restrict__ out, int E)
{
    const int lane = threadIdx.x & 63;
    const int wid = threadIdx.x >> 6;
    const int base = (blockIdx.x * 4 + wid) * 4;
    if (base >= E) return;

    int e[4];
#pragma unroll
    for (int u = 0; u < 4; ++u) {
        int eu = base + u;
        e[u] = eu < E ? eu : E - 1;      // clamp: dup work, identical writes
    }

    const int lo = lane * 4;
    float4 h[4], t[4], g[4];
#pragma unroll
    for (int u = 0; u < 4; ++u) h[u] = *(const float4*)&H[(size_t)ei[e[u]] * EMB + lo];
#pragma unroll
    for (int u = 0; u < 4; ++u) t[u] = *(const float4*)&T[(size_t)ei[E + e[u]] * EMB + lo];
#pragma unroll
    for (int u = 0; u < 4; ++u) g[u] = *(const float4*)&rel[(size_t)et[e[u]] * EMB + lo];

    float p[4];
#pragma unroll
    for (int u = 0; u < 4; ++u)
        p[u] = h[u].x * g[u].x * t[u].x + h[u].y * g[u].y * t[u].y
             + h[u].z * g[u].z * t[u].z + h[u].w * g[u].w * t[u].w;

#pragma unroll
    for (int off = 32; off > 0; off >>= 1) {
#pragma unroll
        for (int u = 0; u < 4; ++u) p[u] += __shfl_xor(p[u], off, 64);
    }
    if (lane == 0) {
#pragma unroll
        for (int u = 0; u < 4; ++u)
            out[e[u]] = 1.0f / (1.0f + expf(-p[u]));
    }
}

// Last-resort fallback: one block per edge, direct fp32 matvecs.
__global__ __launch_bounds__(256)
void edge_direct(const float* __restrict__ X, const int* __restrict__ ei,
                 const int* __restrict__ et,
                 const float* __restrict__ Wh, const float* __restrict__ bh,
                 const float* __restrict__ Wt, const float* __restrict__ bt,
                 const float* __restrict__ rel, float* __restrict__ out, int E)
{
    __shared__ float xsrc[EMB], xdst[EMB];
    __shared__ float red[256];
    const int e = blockIdx.x;
    const int tid = threadIdx.x;
    const int src = ei[e], dst = ei[E + e], r = et[e];

    xsrc[tid] = X[(size_t)src * EMB + tid];
    xdst[tid] = X[(size_t)dst * EMB + tid];
    __syncthreads();

    float ah = 0.f, at = 0.f;
    const float* wh = Wh + (size_t)tid * EMB;
    const float* wt = Wt + (size_t)tid * EMB;
#pragma unroll 8
    for (int k = 0; k < EMB; k += 4) {
        float4 w4 = *(const float4*)&wh[k];
        ah += w4.x * xsrc[k] + w4.y * xsrc[k + 1] + w4.z * xsrc[k + 2] + w4.w * xsrc[k + 3];
        float4 v4 = *(const float4*)&wt[k];
        at += v4.x * xdst[k] + v4.y * xdst[k + 1] + v4.z * xdst[k + 2] + v4.w * xdst[k + 3];
    }
    red[tid] = (ah + bh[tid]) * rel[(size_t)r * EMB + tid] * (at + bt[tid]);
    __syncthreads();
    for (int s2 = 128; s2 > 0; s2 >>= 1) {
        if (tid < s2) red[tid] += red[tid + s2];
        __syncthreads();
    }
    if (tid == 0) out[e] = 1.0f / (1.0f + expf(-red[0]));
}

extern "C" void kernel_launch(void* const* d_in, const int* in_sizes, int n_in,
                              void* d_out, int out_size, void* d_ws, size_t ws_size,
                              hipStream_t stream) {
    const float* x   = (const float*)d_in[0];
    const int*   ei  = (const int*)d_in[1];
    const int*   et  = (const int*)d_in[2];
    const float* Wh  = (const float*)d_in[3];
    const float* bh  = (const float*)d_in[4];
    const float* Wt  = (const float*)d_in[5];
    const float* bt  = (const float*)d_in[6];
    const float* rel = (const float*)d_in[7];
    float* out = (float*)d_out;

    const int M = in_sizes[0] / EMB;   // 100000 nodes
    const int E = in_sizes[2];         // 250000 edges

    const size_t szHT = (size_t)2 * M * EMB * sizeof(float);        // H + T
    const size_t szWs = (size_t)2 * 256 * 512 * sizeof(_Float16);   // Whs+Wts

    if (ws_size >= szHT + szWs) {
        float* H = (float*)d_ws;
        float* T = H + (size_t)M * EMB;
        _Float16* Whs = (_Float16*)((char*)d_ws + szHT);
        _Float16* Wts = Whs + (size_t)256 * 512;

        presplit_w<<<64, 256, 0, stream>>>(Wh, Wt, Whs, Wts);
        const int mtiles = (M + 127) / 128;
        const int nwg = 2 * mtiles;
        gemm_dual<<<nwg, 256, 0, stream>>>(x, Whs, Wts, bh, bt, H, T, M, nwg);
        edge_score4<<<(E + 15) / 16, 256, 0, stream>>>(H, T, rel, ei, et, out, E);
    } else {
        edge_direct<<<E, 256, 0, stream>>>(x, ei, et, Wh, bh, Wt, bt, rel, out, E);
    }
}